// Round 14
// baseline (36.812 us; speedup 1.0000x reference)
//
#include <hip/hip_runtime.h>

// MEASUREMENT ROUND (deliberate, reverts next round): launch K1, K2, K2.
// K2 is idempotent (rewrites identical out), so correctness is unchanged.
// Purpose: D = K1 + 2*K2 + 2*gap; R12 gave K1 + K2 + gap = 24.5us ->
// D - 24.5 = K2 + gap, finally splitting the 24.5us budget that five rounds
// of shape changes couldn't explain (both dispatches are hidden below the
// harness fill kernels in the rocprof top-5).
//
// Kernels are byte-identical to R12 (lr_idx6 TT=256 parallel anchors;
// lr_gather5 fat 8-channel LDS gather).

#define LR_B 32
#define LR_C 256
#define LR_TIN 256
#define LR_TOUT 2048

#define SCAN_TT 256                   // t-interval per K1 block
#define CCHUNK 8                      // channels per K2 block

__global__ __launch_bounds__(512) void lr_idx6(const float* __restrict__ path,
                                               int* __restrict__ idx) {
    __shared__ int o_lo_s, o_hi_s;
    __shared__ int owner[SCAN_TT];

    const int tid = threadIdx.x;
    const int t0 = blockIdx.x * SCAN_TT;
    const int b = blockIdx.y;
    const float* pb = path + (size_t)b * LR_TIN * LR_TOUT;

    // ---- anchor scans: both columns issued in parallel across 8 waves ----
    if (tid < LR_TIN) {
        if (pb[(size_t)tid * LR_TOUT + t0] != 0.0f) o_lo_s = tid;
    } else {
        const int r = tid - LR_TIN;
        if (t0 + SCAN_TT < LR_TOUT) {
            if (pb[(size_t)r * LR_TOUT + t0 + SCAN_TT] != 0.0f) o_hi_s = r;
        } else if (r == 0) {
            o_hi_s = LR_TIN - 1;
        }
    }
    __syncthreads();
    const int o_lo = o_lo_s;
    const int o_hi = o_hi_s;

    // ---- band scan: 8 rows x 64 float4-cols per pass ----
    const int col4 = tid & 63;        // float4 column within the 256-t tile
    const int row_off = tid >> 6;     // 0..7
    for (int r = o_lo + row_off; r <= o_hi; r += 8) {
        const float4 v = *reinterpret_cast<const float4*>(
            pb + (size_t)r * LR_TOUT + t0 + 4 * col4);
        if (v.x != 0.0f) owner[4 * col4 + 0] = r;
        if (v.y != 0.0f) owner[4 * col4 + 1] = r;
        if (v.z != 0.0f) owner[4 * col4 + 2] = r;
        if (v.w != 0.0f) owner[4 * col4 + 3] = r;
    }
    __syncthreads();

    if (tid < SCAN_TT / 4) {
        const int4 o = *reinterpret_cast<const int4*>(&owner[4 * tid]);
        *reinterpret_cast<int4*>(idx + b * LR_TOUT + t0 + 4 * tid) = o;
    }
}

__global__ __launch_bounds__(256) void lr_gather5(const float* __restrict__ x,
                                                  const int* __restrict__ idx,
                                                  float* __restrict__ out) {
    __shared__ float xs[CCHUNK][LR_TIN];   // 8 KiB

    const int c0 = blockIdx.x * CCHUNK;
    const int b = blockIdx.y;
    const int tid = threadIdx.x;

    {
        const float* xb = x + ((size_t)b * LR_C + c0) * LR_TIN;
#pragma unroll
        for (int ch = 0; ch < CCHUNK; ++ch) {
            xs[ch][tid] = xb[(size_t)ch * LR_TIN + tid];
        }
    }

    const int* ib = idx + b * LR_TOUT;
    const int t0 = 4 * tid;
    const int4 iv0 = *reinterpret_cast<const int4*>(ib + t0);
    const int4 iv1 = *reinterpret_cast<const int4*>(ib + t0 + LR_TOUT / 2);
    __syncthreads();

    float* ob = out + ((size_t)b * LR_C + c0) * LR_TOUT;
#pragma unroll
    for (int ch = 0; ch < CCHUNK; ++ch) {
        float4 o0, o1;
        o0.x = xs[ch][iv0.x]; o0.y = xs[ch][iv0.y];
        o0.z = xs[ch][iv0.z]; o0.w = xs[ch][iv0.w];
        o1.x = xs[ch][iv1.x]; o1.y = xs[ch][iv1.y];
        o1.z = xs[ch][iv1.z]; o1.w = xs[ch][iv1.w];
        float* oc = ob + (size_t)ch * LR_TOUT;
        *reinterpret_cast<float4*>(oc + t0) = o0;
        *reinterpret_cast<float4*>(oc + t0 + LR_TOUT / 2) = o1;
    }
}

// Fallback (no workspace): banded fused kernel, correct but slower.
__global__ __launch_bounds__(256) void lr_fused5(const float* __restrict__ x,
                                                 const float* __restrict__ path,
                                                 float* __restrict__ out) {
    __shared__ int owner[64];
    __shared__ int o_lo_s, o_hi_s;
    const int tid = threadIdx.x;
    const int t0 = blockIdx.x * 64;
    const int b  = blockIdx.y;
    const float* pb = path + (size_t)b * LR_TIN * LR_TOUT;

    if (pb[(size_t)tid * LR_TOUT + t0] != 0.0f) o_lo_s = tid;
    if (t0 + 64 < LR_TOUT) {
        if (pb[(size_t)tid * LR_TOUT + t0 + 64] != 0.0f) o_hi_s = tid;
    } else if (tid == 0) {
        o_hi_s = LR_TIN - 1;
    }
    __syncthreads();
    const int o_lo = o_lo_s;
    const int o_hi = o_hi_s;

    const int col4 = tid & 15;
    const int row_off = tid >> 4;
    for (int r = o_lo + row_off; r <= o_hi; r += 16) {
        const float4 v = *reinterpret_cast<const float4*>(
            pb + (size_t)r * LR_TOUT + t0 + 4 * col4);
        if (v.x != 0.0f) owner[4 * col4 + 0] = r;
        if (v.y != 0.0f) owner[4 * col4 + 1] = r;
        if (v.z != 0.0f) owner[4 * col4 + 2] = r;
        if (v.w != 0.0f) owner[4 * col4 + 3] = r;
    }
    __syncthreads();

    const int4 iv = *reinterpret_cast<const int4*>(&owner[4 * col4]);
    const int cbase = tid >> 4;
    const float* xb = x + (size_t)b * LR_C * LR_TIN;
    float* ob = out + (size_t)b * LR_C * LR_TOUT + t0 + 4 * col4;
#pragma unroll
    for (int j = 0; j < LR_C / 16; ++j) {
        const int c = cbase + 16 * j;
        const float* xr = xb + (size_t)c * LR_TIN;
        float4 o;
        o.x = xr[iv.x]; o.y = xr[iv.y]; o.z = xr[iv.z]; o.w = xr[iv.w];
        *reinterpret_cast<float4*>(ob + (size_t)c * LR_TOUT) = o;
    }
}

extern "C" void kernel_launch(void* const* d_in, const int* in_sizes, int n_in,
                              void* d_out, int out_size, void* d_ws, size_t ws_size,
                              hipStream_t stream) {
    const float* x    = (const float*)d_in[0];   // [B, C, T_IN] fp32
    const float* path = (const float*)d_in[1];   // [B, T_IN, T_OUT] fp32
    float* out = (float*)d_out;                  // [B, C, T_OUT] fp32

    const size_t idx_bytes = (size_t)LR_B * LR_TOUT * sizeof(int);
    if (ws_size >= idx_bytes) {
        int* idx = (int*)d_ws;
        lr_idx6<<<dim3(LR_TOUT / SCAN_TT, LR_B), 512, 0, stream>>>(path, idx);
        lr_gather5<<<dim3(LR_C / CCHUNK, LR_B), 256, 0, stream>>>(x, idx, out);
        // measurement: run K2 a second time (idempotent rewrite of out)
        lr_gather5<<<dim3(LR_C / CCHUNK, LR_B), 256, 0, stream>>>(x, idx, out);
    } else {
        lr_fused5<<<dim3(LR_TOUT / 64, LR_B), 256, 0, stream>>>(x, path, out);
    }
}

// Round 15
// 26.689 us; speedup vs baseline: 1.3793x; 1.3793x over previous
//
#include <hip/hip_runtime.h>

// LengthRegulator: out[b,c,t] = x[b,c,owner(b,t)]; owner is the unique token
// whose segment covers frame t (path = 0/1 disjoint segment mask tiling
// [0,T_OUT) -> bmm(x,path) == gather; exact). owner(b,t) monotone in t.
//
// R14 measurement: K1(anchors+band) ~= 12us, K2 ~= 11.5us (write floor).
// K1's cost is the scattered anchor reads (131K distinct 64B lines, with
// each tile's hi column duplicating the neighbor's lo). Split K1:
//
// K0 (anchor): thread (k,b,r) reads path[b,r,256k] (one scattered load per
//   thread, whole-GPU scatter in flight at once); the unique hitting row
//   stores anchor[b][k]. 8 columns/b instead of 16 -> half the scatter.
// K1 (band): bounds from anchor[] (L2-resident): lo=anchor[b][k],
//   hi = (k==7) ? 255 : anchor[b][k+1]; band scan ~33 rows of coalesced
//   float4 row-slices; race-free conditional LDS store; idx write.
// K2 (fat gather, unchanged): block per (b, 8-channel chunk); 8 x-rows in
//   LDS; idx int4s in registers; 1 KiB contiguous wave stores.

#define LR_B 32
#define LR_C 256
#define LR_TIN 256
#define LR_TOUT 2048

#define SCAN_TT 256                   // t-interval per band block
#define NTILE (LR_TOUT / SCAN_TT)     // 8
#define CCHUNK 8                      // channels per K2 block

__global__ __launch_bounds__(256) void lr_anchor(const float* __restrict__ path,
                                                 int* __restrict__ anchor) {
    const int k = blockIdx.x;         // anchor column 0..7 (t = 256k)
    const int b = blockIdx.y;
    const int r = threadIdx.x;        // row
    if (path[((size_t)b * LR_TIN + r) * LR_TOUT + k * SCAN_TT] != 0.0f)
        anchor[b * NTILE + k] = r;    // exactly one r hits per (b,k)
}

__global__ __launch_bounds__(512) void lr_band(const float* __restrict__ path,
                                               const int* __restrict__ anchor,
                                               int* __restrict__ idx) {
    __shared__ int owner[SCAN_TT];

    const int tid = threadIdx.x;
    const int k = blockIdx.x;         // tile 0..7
    const int b = blockIdx.y;
    const int t0 = k * SCAN_TT;
    const float* pb = path + (size_t)b * LR_TIN * LR_TOUT;

    const int o_lo = anchor[b * NTILE + k];
    const int o_hi = (k == NTILE - 1) ? (LR_TIN - 1) : anchor[b * NTILE + k + 1];

    // band scan: 8 rows x 64 float4-cols per pass
    const int col4 = tid & 63;        // float4 column within the 256-t tile
    const int row_off = tid >> 6;     // 0..7
    for (int r = o_lo + row_off; r <= o_hi; r += 8) {
        const float4 v = *reinterpret_cast<const float4*>(
            pb + (size_t)r * LR_TOUT + t0 + 4 * col4);
        if (v.x != 0.0f) owner[4 * col4 + 0] = r;
        if (v.y != 0.0f) owner[4 * col4 + 1] = r;
        if (v.z != 0.0f) owner[4 * col4 + 2] = r;
        if (v.w != 0.0f) owner[4 * col4 + 3] = r;
    }
    __syncthreads();

    if (tid < SCAN_TT / 4) {
        const int4 o = *reinterpret_cast<const int4*>(&owner[4 * tid]);
        *reinterpret_cast<int4*>(idx + b * LR_TOUT + t0 + 4 * tid) = o;
    }
}

__global__ __launch_bounds__(256) void lr_gather5(const float* __restrict__ x,
                                                  const int* __restrict__ idx,
                                                  float* __restrict__ out) {
    __shared__ float xs[CCHUNK][LR_TIN];   // 8 KiB

    const int c0 = blockIdx.x * CCHUNK;
    const int b = blockIdx.y;
    const int tid = threadIdx.x;

    {
        const float* xb = x + ((size_t)b * LR_C + c0) * LR_TIN;
#pragma unroll
        for (int ch = 0; ch < CCHUNK; ++ch) {
            xs[ch][tid] = xb[(size_t)ch * LR_TIN + tid];
        }
    }

    const int* ib = idx + b * LR_TOUT;
    const int t0 = 4 * tid;
    const int4 iv0 = *reinterpret_cast<const int4*>(ib + t0);
    const int4 iv1 = *reinterpret_cast<const int4*>(ib + t0 + LR_TOUT / 2);
    __syncthreads();

    float* ob = out + ((size_t)b * LR_C + c0) * LR_TOUT;
#pragma unroll
    for (int ch = 0; ch < CCHUNK; ++ch) {
        float4 o0, o1;
        o0.x = xs[ch][iv0.x]; o0.y = xs[ch][iv0.y];
        o0.z = xs[ch][iv0.z]; o0.w = xs[ch][iv0.w];
        o1.x = xs[ch][iv1.x]; o1.y = xs[ch][iv1.y];
        o1.z = xs[ch][iv1.z]; o1.w = xs[ch][iv1.w];
        float* oc = ob + (size_t)ch * LR_TOUT;
        *reinterpret_cast<float4*>(oc + t0) = o0;
        *reinterpret_cast<float4*>(oc + t0 + LR_TOUT / 2) = o1;
    }
}

// Fallback (no workspace): banded fused kernel, correct but slower.
__global__ __launch_bounds__(256) void lr_fused5(const float* __restrict__ x,
                                                 const float* __restrict__ path,
                                                 float* __restrict__ out) {
    __shared__ int owner[64];
    __shared__ int o_lo_s, o_hi_s;
    const int tid = threadIdx.x;
    const int t0 = blockIdx.x * 64;
    const int b  = blockIdx.y;
    const float* pb = path + (size_t)b * LR_TIN * LR_TOUT;

    if (pb[(size_t)tid * LR_TOUT + t0] != 0.0f) o_lo_s = tid;
    if (t0 + 64 < LR_TOUT) {
        if (pb[(size_t)tid * LR_TOUT + t0 + 64] != 0.0f) o_hi_s = tid;
    } else if (tid == 0) {
        o_hi_s = LR_TIN - 1;
    }
    __syncthreads();
    const int o_lo = o_lo_s;
    const int o_hi = o_hi_s;

    const int col4 = tid & 15;
    const int row_off = tid >> 4;
    for (int r = o_lo + row_off; r <= o_hi; r += 16) {
        const float4 v = *reinterpret_cast<const float4*>(
            pb + (size_t)r * LR_TOUT + t0 + 4 * col4);
        if (v.x != 0.0f) owner[4 * col4 + 0] = r;
        if (v.y != 0.0f) owner[4 * col4 + 1] = r;
        if (v.z != 0.0f) owner[4 * col4 + 2] = r;
        if (v.w != 0.0f) owner[4 * col4 + 3] = r;
    }
    __syncthreads();

    const int4 iv = *reinterpret_cast<const int4*>(&owner[4 * col4]);
    const int cbase = tid >> 4;
    const float* xb = x + (size_t)b * LR_C * LR_TIN;
    float* ob = out + (size_t)b * LR_C * LR_TOUT + t0 + 4 * col4;
#pragma unroll
    for (int j = 0; j < LR_C / 16; ++j) {
        const int c = cbase + 16 * j;
        const float* xr = xb + (size_t)c * LR_TIN;
        float4 o;
        o.x = xr[iv.x]; o.y = xr[iv.y]; o.z = xr[iv.z]; o.w = xr[iv.w];
        *reinterpret_cast<float4*>(ob + (size_t)c * LR_TOUT) = o;
    }
}

extern "C" void kernel_launch(void* const* d_in, const int* in_sizes, int n_in,
                              void* d_out, int out_size, void* d_ws, size_t ws_size,
                              hipStream_t stream) {
    const float* x    = (const float*)d_in[0];   // [B, C, T_IN] fp32
    const float* path = (const float*)d_in[1];   // [B, T_IN, T_OUT] fp32
    float* out = (float*)d_out;                  // [B, C, T_OUT] fp32

    const size_t idx_bytes = (size_t)LR_B * LR_TOUT * sizeof(int);
    const size_t anchor_bytes = (size_t)LR_B * NTILE * sizeof(int);
    if (ws_size >= idx_bytes + anchor_bytes) {
        int* idx = (int*)d_ws;
        int* anchor = (int*)((char*)d_ws + idx_bytes);
        lr_anchor<<<dim3(NTILE, LR_B), 256, 0, stream>>>(path, anchor);
        lr_band<<<dim3(NTILE, LR_B), 512, 0, stream>>>(path, anchor, idx);
        lr_gather5<<<dim3(LR_C / CCHUNK, LR_B), 256, 0, stream>>>(x, idx, out);
    } else {
        lr_fused5<<<dim3(LR_TOUT / 64, LR_B), 256, 0, stream>>>(x, path, out);
    }
}

// Round 16
// 24.552 us; speedup vs baseline: 1.4993x; 1.0870x over previous
//
#include <hip/hip_runtime.h>

// LengthRegulator: out[b,c,t] = x[b,c,owner(b,t)]; owner is the unique token
// whose segment covers frame t (path = 0/1 disjoint segment mask tiling
// [0,T_OUT) -> bmm(x,path) == gather; exact). owner(b,t) monotone in t.
//
// R14/R15 measurements: K2 ~= 11.5us (write floor). K1 ~= 12us regardless of
// anchor restructuring -> scattered one-hot column probes (64B lines at 8KiB
// stride, one DRAM page activation each) are activation-THROUGHPUT-bound.
// Fix: no scattered probes at all.
//
// K1 (diagonal-band idx build): durations ~ floor(U[0.1,1.1]/S*2048) -> mean
// step ~7.5 frames, so owner(t) ~= t/7.5 (= 2t/15) with random-walk sigma
// <= ~8 rows. Scan only rows [2*t0/15 - PAD, 2*(t0+255)/15 + PAD], PAD=26
// (>3 sigma): ~75 rows of COALESCED 1 KiB row-slices per 256-t tile
// (~19 MiB total, 16x better DRAM-page amortization than 64B probes).
// Correctness does NOT depend on the statistics: owner[] init to -1; after
// the scan the block verifies all 256 t's found an owner; if any missing,
// widen band 64 rows/side and rescan (terminates at full range = exhaustive
// scan). Race-free conditional LDS stores (exactly one nonzero per t).
//
// K2 (fat gather, unchanged): block per (b, 8-channel chunk); 8 x-rows in
// LDS; idx int4s in registers; 1 KiB contiguous wave stores.

#define LR_B 32
#define LR_C 256
#define LR_TIN 256
#define LR_TOUT 2048

#define SCAN_TT 256                   // t-interval per K1 block
#define NTILE (LR_TOUT / SCAN_TT)     // 8
#define PAD 26                        // band half-width margin (rows)
#define CCHUNK 8                      // channels per K2 block

__global__ __launch_bounds__(512) void lr_idx7(const float* __restrict__ path,
                                               int* __restrict__ idx) {
    __shared__ int owner[SCAN_TT];
    __shared__ int missing_s;

    const int tid = threadIdx.x;
    const int k = blockIdx.x;         // tile 0..7
    const int b = blockIdx.y;
    const int t0 = k * SCAN_TT;
    const float* pb = path + (size_t)b * LR_TIN * LR_TOUT;

    if (tid < SCAN_TT) owner[tid] = -1;
    __syncthreads();

    // statistical band estimate: owner(t) ~ 2t/15
    int rlo = (2 * t0) / 15 - PAD;
    int rhi = (2 * (t0 + SCAN_TT - 1)) / 15 + PAD;
    rlo = rlo < 0 ? 0 : rlo;
    rhi = rhi > LR_TIN - 1 ? LR_TIN - 1 : rhi;

    const int col4 = tid & 63;        // float4 column within the 256-t tile
    const int row_off = tid >> 6;     // 0..7

    for (int attempt = 0; attempt < 6; ++attempt) {
        for (int r = rlo + row_off; r <= rhi; r += 8) {
            const float4 v = *reinterpret_cast<const float4*>(
                pb + (size_t)r * LR_TOUT + t0 + 4 * col4);
            if (v.x != 0.0f) owner[4 * col4 + 0] = r;
            if (v.y != 0.0f) owner[4 * col4 + 1] = r;
            if (v.z != 0.0f) owner[4 * col4 + 2] = r;
            if (v.w != 0.0f) owner[4 * col4 + 3] = r;
        }
        if (tid == 0) missing_s = 0;
        __syncthreads();
        if (tid < SCAN_TT && owner[tid] < 0) missing_s = 1;  // benign race
        __syncthreads();
        if (missing_s == 0) break;
        const int nlo = rlo - 64 < 0 ? 0 : rlo - 64;
        const int nhi = rhi + 64 > LR_TIN - 1 ? LR_TIN - 1 : rhi + 64;
        if (nlo == rlo && nhi == rhi) break;   // full range already scanned
        rlo = nlo;
        rhi = nhi;
        __syncthreads();
    }

    if (tid < SCAN_TT / 4) {
        const int4 o = *reinterpret_cast<const int4*>(&owner[4 * tid]);
        *reinterpret_cast<int4*>(idx + b * LR_TOUT + t0 + 4 * tid) = o;
    }
}

__global__ __launch_bounds__(256) void lr_gather5(const float* __restrict__ x,
                                                  const int* __restrict__ idx,
                                                  float* __restrict__ out) {
    __shared__ float xs[CCHUNK][LR_TIN];   // 8 KiB

    const int c0 = blockIdx.x * CCHUNK;
    const int b = blockIdx.y;
    const int tid = threadIdx.x;

    {
        const float* xb = x + ((size_t)b * LR_C + c0) * LR_TIN;
#pragma unroll
        for (int ch = 0; ch < CCHUNK; ++ch) {
            xs[ch][tid] = xb[(size_t)ch * LR_TIN + tid];
        }
    }

    const int* ib = idx + b * LR_TOUT;
    const int t0 = 4 * tid;
    const int4 iv0 = *reinterpret_cast<const int4*>(ib + t0);
    const int4 iv1 = *reinterpret_cast<const int4*>(ib + t0 + LR_TOUT / 2);
    __syncthreads();

    float* ob = out + ((size_t)b * LR_C + c0) * LR_TOUT;
#pragma unroll
    for (int ch = 0; ch < CCHUNK; ++ch) {
        float4 o0, o1;
        o0.x = xs[ch][iv0.x]; o0.y = xs[ch][iv0.y];
        o0.z = xs[ch][iv0.z]; o0.w = xs[ch][iv0.w];
        o1.x = xs[ch][iv1.x]; o1.y = xs[ch][iv1.y];
        o1.z = xs[ch][iv1.z]; o1.w = xs[ch][iv1.w];
        float* oc = ob + (size_t)ch * LR_TOUT;
        *reinterpret_cast<float4*>(oc + t0) = o0;
        *reinterpret_cast<float4*>(oc + t0 + LR_TOUT / 2) = o1;
    }
}

// Fallback (no workspace): banded fused kernel, correct but slower.
__global__ __launch_bounds__(256) void lr_fused5(const float* __restrict__ x,
                                                 const float* __restrict__ path,
                                                 float* __restrict__ out) {
    __shared__ int owner[64];
    __shared__ int o_lo_s, o_hi_s;
    const int tid = threadIdx.x;
    const int t0 = blockIdx.x * 64;
    const int b  = blockIdx.y;
    const float* pb = path + (size_t)b * LR_TIN * LR_TOUT;

    if (pb[(size_t)tid * LR_TOUT + t0] != 0.0f) o_lo_s = tid;
    if (t0 + 64 < LR_TOUT) {
        if (pb[(size_t)tid * LR_TOUT + t0 + 64] != 0.0f) o_hi_s = tid;
    } else if (tid == 0) {
        o_hi_s = LR_TIN - 1;
    }
    __syncthreads();
    const int o_lo = o_lo_s;
    const int o_hi = o_hi_s;

    const int col4 = tid & 15;
    const int row_off = tid >> 4;
    for (int r = o_lo + row_off; r <= o_hi; r += 16) {
        const float4 v = *reinterpret_cast<const float4*>(
            pb + (size_t)r * LR_TOUT + t0 + 4 * col4);
        if (v.x != 0.0f) owner[4 * col4 + 0] = r;
        if (v.y != 0.0f) owner[4 * col4 + 1] = r;
        if (v.z != 0.0f) owner[4 * col4 + 2] = r;
        if (v.w != 0.0f) owner[4 * col4 + 3] = r;
    }
    __syncthreads();

    const int4 iv = *reinterpret_cast<const int4*>(&owner[4 * col4]);
    const int cbase = tid >> 4;
    const float* xb = x + (size_t)b * LR_C * LR_TIN;
    float* ob = out + (size_t)b * LR_C * LR_TOUT + t0 + 4 * col4;
#pragma unroll
    for (int j = 0; j < LR_C / 16; ++j) {
        const int c = cbase + 16 * j;
        const float* xr = xb + (size_t)c * LR_TIN;
        float4 o;
        o.x = xr[iv.x]; o.y = xr[iv.y]; o.z = xr[iv.z]; o.w = xr[iv.w];
        *reinterpret_cast<float4*>(ob + (size_t)c * LR_TOUT) = o;
    }
}

extern "C" void kernel_launch(void* const* d_in, const int* in_sizes, int n_in,
                              void* d_out, int out_size, void* d_ws, size_t ws_size,
                              hipStream_t stream) {
    const float* x    = (const float*)d_in[0];   // [B, C, T_IN] fp32
    const float* path = (const float*)d_in[1];   // [B, T_IN, T_OUT] fp32
    float* out = (float*)d_out;                  // [B, C, T_OUT] fp32

    const size_t idx_bytes = (size_t)LR_B * LR_TOUT * sizeof(int);
    if (ws_size >= idx_bytes) {
        int* idx = (int*)d_ws;
        lr_idx7<<<dim3(NTILE, LR_B), 512, 0, stream>>>(path, idx);
        lr_gather5<<<dim3(LR_C / CCHUNK, LR_B), 256, 0, stream>>>(x, idx, out);
    } else {
        lr_fused5<<<dim3(LR_TOUT / 64, LR_B), 256, 0, stream>>>(x, path, out);
    }
}

// Round 17
// 23.091 us; speedup vs baseline: 1.5942x; 1.0633x over previous
//
#include <hip/hip_runtime.h>

// LengthRegulator: out[b,c,t] = x[b,c,owner(b,t)]; owner is the unique token
// whose segment covers frame t (path = 0/1 disjoint segment mask tiling
// [0,T_OUT) -> bmm(x,path) == gather; exact). owner(b,t) monotone in t.
//
// Budget (R12/R14/R16 algebra): K2 = 11.6us traffic floor; gap ~0.7us;
// K1 ~11.5us for ~3us of bytes regardless of structure -> K1 is
// latency/occupancy-bound (2048 waves @ ~11 serial load-iterations each).
//
// K1 v8: SCAN_TT=64, 512 threads -> 32 rows/pass, diagonal band
// (owner(t) ~= 2t/15, PAD=24 ~ 4 sigma of the duration random-walk) gives
// ~57 rows = 2 passes/wave; grid 32x32 = 1024 blocks x 8 waves = 8192 waves
// (100% wave occupancy). Correctness independent of statistics: owner[] init
// -1, per-block verify, widen-by-64 rescan fallback (terminates at full
// range = exhaustive scan). Race-free conditional LDS stores.
//
// K2 (fat gather, unchanged): block per (b, 8-channel chunk); 8 x-rows in
// LDS; idx int4s in registers; 1 KiB contiguous wave stores.

#define LR_B 32
#define LR_C 256
#define LR_TIN 256
#define LR_TOUT 2048

#define SCAN_TT 64                    // t-interval per K1 block
#define NTILE (LR_TOUT / SCAN_TT)     // 32
#define PAD 24                        // band half-width margin (rows)
#define CCHUNK 8                      // channels per K2 block

__global__ __launch_bounds__(512) void lr_idx8(const float* __restrict__ path,
                                               int* __restrict__ idx) {
    __shared__ int owner[SCAN_TT];
    __shared__ int missing_s;

    const int tid = threadIdx.x;
    const int k = blockIdx.x;         // tile 0..31
    const int b = blockIdx.y;
    const int t0 = k * SCAN_TT;
    const float* pb = path + (size_t)b * LR_TIN * LR_TOUT;

    if (tid < SCAN_TT) owner[tid] = -1;
    __syncthreads();

    // statistical band estimate: owner(t) ~ 2t/15
    int rlo = (2 * t0) / 15 - PAD;
    int rhi = (2 * (t0 + SCAN_TT - 1)) / 15 + PAD;
    rlo = rlo < 0 ? 0 : rlo;
    rhi = rhi > LR_TIN - 1 ? LR_TIN - 1 : rhi;

    const int col4 = tid & 15;        // float4 column within the 64-t tile
    const int row_off = tid >> 4;     // 0..31

    for (int attempt = 0; attempt < 10; ++attempt) {
        for (int r = rlo + row_off; r <= rhi; r += 32) {
            const float4 v = *reinterpret_cast<const float4*>(
                pb + (size_t)r * LR_TOUT + t0 + 4 * col4);
            if (v.x != 0.0f) owner[4 * col4 + 0] = r;
            if (v.y != 0.0f) owner[4 * col4 + 1] = r;
            if (v.z != 0.0f) owner[4 * col4 + 2] = r;
            if (v.w != 0.0f) owner[4 * col4 + 3] = r;
        }
        if (tid == 0) missing_s = 0;
        __syncthreads();
        if (tid < SCAN_TT && owner[tid] < 0) missing_s = 1;  // benign race
        __syncthreads();
        if (missing_s == 0) break;
        const int nlo = rlo - 64 < 0 ? 0 : rlo - 64;
        const int nhi = rhi + 64 > LR_TIN - 1 ? LR_TIN - 1 : rhi + 64;
        if (nlo == rlo && nhi == rhi) break;   // full range already scanned
        rlo = nlo;
        rhi = nhi;
        __syncthreads();
    }

    if (tid < SCAN_TT / 4) {
        const int4 o = *reinterpret_cast<const int4*>(&owner[4 * tid]);
        *reinterpret_cast<int4*>(idx + b * LR_TOUT + t0 + 4 * tid) = o;
    }
}

__global__ __launch_bounds__(256) void lr_gather5(const float* __restrict__ x,
                                                  const int* __restrict__ idx,
                                                  float* __restrict__ out) {
    __shared__ float xs[CCHUNK][LR_TIN];   // 8 KiB

    const int c0 = blockIdx.x * CCHUNK;
    const int b = blockIdx.y;
    const int tid = threadIdx.x;

    {
        const float* xb = x + ((size_t)b * LR_C + c0) * LR_TIN;
#pragma unroll
        for (int ch = 0; ch < CCHUNK; ++ch) {
            xs[ch][tid] = xb[(size_t)ch * LR_TIN + tid];
        }
    }

    const int* ib = idx + b * LR_TOUT;
    const int t0 = 4 * tid;
    const int4 iv0 = *reinterpret_cast<const int4*>(ib + t0);
    const int4 iv1 = *reinterpret_cast<const int4*>(ib + t0 + LR_TOUT / 2);
    __syncthreads();

    float* ob = out + ((size_t)b * LR_C + c0) * LR_TOUT;
#pragma unroll
    for (int ch = 0; ch < CCHUNK; ++ch) {
        float4 o0, o1;
        o0.x = xs[ch][iv0.x]; o0.y = xs[ch][iv0.y];
        o0.z = xs[ch][iv0.z]; o0.w = xs[ch][iv0.w];
        o1.x = xs[ch][iv1.x]; o1.y = xs[ch][iv1.y];
        o1.z = xs[ch][iv1.z]; o1.w = xs[ch][iv1.w];
        float* oc = ob + (size_t)ch * LR_TOUT;
        *reinterpret_cast<float4*>(oc + t0) = o0;
        *reinterpret_cast<float4*>(oc + t0 + LR_TOUT / 2) = o1;
    }
}

// Fallback (no workspace): banded fused kernel, correct but slower.
__global__ __launch_bounds__(256) void lr_fused5(const float* __restrict__ x,
                                                 const float* __restrict__ path,
                                                 float* __restrict__ out) {
    __shared__ int owner[64];
    __shared__ int o_lo_s, o_hi_s;
    const int tid = threadIdx.x;
    const int t0 = blockIdx.x * 64;
    const int b  = blockIdx.y;
    const float* pb = path + (size_t)b * LR_TIN * LR_TOUT;

    if (pb[(size_t)tid * LR_TOUT + t0] != 0.0f) o_lo_s = tid;
    if (t0 + 64 < LR_TOUT) {
        if (pb[(size_t)tid * LR_TOUT + t0 + 64] != 0.0f) o_hi_s = tid;
    } else if (tid == 0) {
        o_hi_s = LR_TIN - 1;
    }
    __syncthreads();
    const int o_lo = o_lo_s;
    const int o_hi = o_hi_s;

    const int col4 = tid & 15;
    const int row_off = tid >> 4;
    for (int r = o_lo + row_off; r <= o_hi; r += 16) {
        const float4 v = *reinterpret_cast<const float4*>(
            pb + (size_t)r * LR_TOUT + t0 + 4 * col4);
        if (v.x != 0.0f) owner[4 * col4 + 0] = r;
        if (v.y != 0.0f) owner[4 * col4 + 1] = r;
        if (v.z != 0.0f) owner[4 * col4 + 2] = r;
        if (v.w != 0.0f) owner[4 * col4 + 3] = r;
    }
    __syncthreads();

    const int4 iv = *reinterpret_cast<const int4*>(&owner[4 * col4]);
    const int cbase = tid >> 4;
    const float* xb = x + (size_t)b * LR_C * LR_TIN;
    float* ob = out + (size_t)b * LR_C * LR_TOUT + t0 + 4 * col4;
#pragma unroll
    for (int j = 0; j < LR_C / 16; ++j) {
        const int c = cbase + 16 * j;
        const float* xr = xb + (size_t)c * LR_TIN;
        float4 o;
        o.x = xr[iv.x]; o.y = xr[iv.y]; o.z = xr[iv.z]; o.w = xr[iv.w];
        *reinterpret_cast<float4*>(ob + (size_t)c * LR_TOUT) = o;
    }
}

extern "C" void kernel_launch(void* const* d_in, const int* in_sizes, int n_in,
                              void* d_out, int out_size, void* d_ws, size_t ws_size,
                              hipStream_t stream) {
    const float* x    = (const float*)d_in[0];   // [B, C, T_IN] fp32
    const float* path = (const float*)d_in[1];   // [B, T_IN, T_OUT] fp32
    float* out = (float*)d_out;                  // [B, C, T_OUT] fp32

    const size_t idx_bytes = (size_t)LR_B * LR_TOUT * sizeof(int);
    if (ws_size >= idx_bytes) {
        int* idx = (int*)d_ws;
        lr_idx8<<<dim3(NTILE, LR_B), 512, 0, stream>>>(path, idx);
        lr_gather5<<<dim3(LR_C / CCHUNK, LR_B), 256, 0, stream>>>(x, idx, out);
    } else {
        lr_fused5<<<dim3(LR_TOUT / 64, LR_B), 256, 0, stream>>>(x, path, out);
    }
}

// Round 18
// 22.598 us; speedup vs baseline: 1.6290x; 1.0218x over previous
//
#include <hip/hip_runtime.h>

// LengthRegulator: out[b,c,t] = x[b,c,owner(b,t)]; owner is the unique token
// whose segment covers frame t (path = 0/1 disjoint segment mask tiling
// [0,T_OUT) -> bmm(x,path) == gather; exact). owner(b,t) monotone in t.
//
// Budget (R12/R13/R17 algebra): fixed per-replay cost F ~7-8us (graph replay
// + 2 launches + drain); K2 = 12.3us measured, at its traffic floor
// (64 MiB out-write @ fill rate + x/idx reads); K1 traffic ~2.4us.
// Floor ~= 21.5-22us.
//
// K1 v9 (depth-1 diagonal band): TT=32, 512 threads -> 64 rows covered per
// pass vs ~44-row band (owner(t) ~= 2t/15, PAD=20 ~ 5 sigma) -> every thread
// issues exactly ONE band load; 2048 blocks x 8 waves = 16384 waves, all
// latency overlapped. Correctness independent of statistics: owner[] init
// -1, per-block verify, widen-by-64 rescan (terminates at exhaustive scan).
// Race-free conditional LDS stores (exactly one nonzero per t).
//
// K2 (fat gather, unchanged, at floor): block per (b, 8-channel chunk);
// 8 x-rows in LDS; idx int4s in registers; 1 KiB contiguous wave stores.

#define LR_B 32
#define LR_C 256
#define LR_TIN 256
#define LR_TOUT 2048

#define SCAN_TT 32                    // t-interval per K1 block
#define NTILE (LR_TOUT / SCAN_TT)     // 64
#define PAD 20                        // band half-width margin (rows)
#define CCHUNK 8                      // channels per K2 block

__global__ __launch_bounds__(512) void lr_idx9(const float* __restrict__ path,
                                               int* __restrict__ idx) {
    __shared__ int owner[SCAN_TT];
    __shared__ int missing_s;

    const int tid = threadIdx.x;
    const int k = blockIdx.x;         // tile 0..63
    const int b = blockIdx.y;
    const int t0 = k * SCAN_TT;
    const float* pb = path + (size_t)b * LR_TIN * LR_TOUT;

    if (tid < SCAN_TT) owner[tid] = -1;
    __syncthreads();

    // statistical band estimate: owner(t) ~ 2t/15
    int rlo = (2 * t0) / 15 - PAD;
    int rhi = (2 * (t0 + SCAN_TT - 1)) / 15 + PAD;
    rlo = rlo < 0 ? 0 : rlo;
    rhi = rhi > LR_TIN - 1 ? LR_TIN - 1 : rhi;

    const int col4 = tid & 7;         // float4 column within the 32-t tile
    const int row_off = tid >> 3;     // 0..63

    for (int attempt = 0; attempt < 6; ++attempt) {
        for (int r = rlo + row_off; r <= rhi; r += 64) {   // 1 pass typical
            const float4 v = *reinterpret_cast<const float4*>(
                pb + (size_t)r * LR_TOUT + t0 + 4 * col4);
            if (v.x != 0.0f) owner[4 * col4 + 0] = r;
            if (v.y != 0.0f) owner[4 * col4 + 1] = r;
            if (v.z != 0.0f) owner[4 * col4 + 2] = r;
            if (v.w != 0.0f) owner[4 * col4 + 3] = r;
        }
        if (tid == 0) missing_s = 0;
        __syncthreads();
        if (tid < SCAN_TT && owner[tid] < 0) missing_s = 1;  // benign race
        __syncthreads();
        if (missing_s == 0) break;
        const int nlo = rlo - 64 < 0 ? 0 : rlo - 64;
        const int nhi = rhi + 64 > LR_TIN - 1 ? LR_TIN - 1 : rhi + 64;
        if (nlo == rlo && nhi == rhi) break;   // full range already scanned
        rlo = nlo;
        rhi = nhi;
        __syncthreads();
    }

    if (tid < SCAN_TT / 4) {
        const int4 o = *reinterpret_cast<const int4*>(&owner[4 * tid]);
        *reinterpret_cast<int4*>(idx + b * LR_TOUT + t0 + 4 * tid) = o;
    }
}

__global__ __launch_bounds__(256) void lr_gather5(const float* __restrict__ x,
                                                  const int* __restrict__ idx,
                                                  float* __restrict__ out) {
    __shared__ float xs[CCHUNK][LR_TIN];   // 8 KiB

    const int c0 = blockIdx.x * CCHUNK;
    const int b = blockIdx.y;
    const int tid = threadIdx.x;

    {
        const float* xb = x + ((size_t)b * LR_C + c0) * LR_TIN;
#pragma unroll
        for (int ch = 0; ch < CCHUNK; ++ch) {
            xs[ch][tid] = xb[(size_t)ch * LR_TIN + tid];
        }
    }

    const int* ib = idx + b * LR_TOUT;
    const int t0 = 4 * tid;
    const int4 iv0 = *reinterpret_cast<const int4*>(ib + t0);
    const int4 iv1 = *reinterpret_cast<const int4*>(ib + t0 + LR_TOUT / 2);
    __syncthreads();

    float* ob = out + ((size_t)b * LR_C + c0) * LR_TOUT;
#pragma unroll
    for (int ch = 0; ch < CCHUNK; ++ch) {
        float4 o0, o1;
        o0.x = xs[ch][iv0.x]; o0.y = xs[ch][iv0.y];
        o0.z = xs[ch][iv0.z]; o0.w = xs[ch][iv0.w];
        o1.x = xs[ch][iv1.x]; o1.y = xs[ch][iv1.y];
        o1.z = xs[ch][iv1.z]; o1.w = xs[ch][iv1.w];
        float* oc = ob + (size_t)ch * LR_TOUT;
        *reinterpret_cast<float4*>(oc + t0) = o0;
        *reinterpret_cast<float4*>(oc + t0 + LR_TOUT / 2) = o1;
    }
}

// Fallback (no workspace): banded fused kernel, correct but slower.
__global__ __launch_bounds__(256) void lr_fused5(const float* __restrict__ x,
                                                 const float* __restrict__ path,
                                                 float* __restrict__ out) {
    __shared__ int owner[64];
    __shared__ int o_lo_s, o_hi_s;
    const int tid = threadIdx.x;
    const int t0 = blockIdx.x * 64;
    const int b  = blockIdx.y;
    const float* pb = path + (size_t)b * LR_TIN * LR_TOUT;

    if (pb[(size_t)tid * LR_TOUT + t0] != 0.0f) o_lo_s = tid;
    if (t0 + 64 < LR_TOUT) {
        if (pb[(size_t)tid * LR_TOUT + t0 + 64] != 0.0f) o_hi_s = tid;
    } else if (tid == 0) {
        o_hi_s = LR_TIN - 1;
    }
    __syncthreads();
    const int o_lo = o_lo_s;
    const int o_hi = o_hi_s;

    const int col4 = tid & 15;
    const int row_off = tid >> 4;
    for (int r = o_lo + row_off; r <= o_hi; r += 16) {
        const float4 v = *reinterpret_cast<const float4*>(
            pb + (size_t)r * LR_TOUT + t0 + 4 * col4);
        if (v.x != 0.0f) owner[4 * col4 + 0] = r;
        if (v.y != 0.0f) owner[4 * col4 + 1] = r;
        if (v.z != 0.0f) owner[4 * col4 + 2] = r;
        if (v.w != 0.0f) owner[4 * col4 + 3] = r;
    }
    __syncthreads();

    const int4 iv = *reinterpret_cast<const int4*>(&owner[4 * col4]);
    const int cbase = tid >> 4;
    const float* xb = x + (size_t)b * LR_C * LR_TIN;
    float* ob = out + (size_t)b * LR_C * LR_TOUT + t0 + 4 * col4;
#pragma unroll
    for (int j = 0; j < LR_C / 16; ++j) {
        const int c = cbase + 16 * j;
        const float* xr = xb + (size_t)c * LR_TIN;
        float4 o;
        o.x = xr[iv.x]; o.y = xr[iv.y]; o.z = xr[iv.z]; o.w = xr[iv.w];
        *reinterpret_cast<float4*>(ob + (size_t)c * LR_TOUT) = o;
    }
}

extern "C" void kernel_launch(void* const* d_in, const int* in_sizes, int n_in,
                              void* d_out, int out_size, void* d_ws, size_t ws_size,
                              hipStream_t stream) {
    const float* x    = (const float*)d_in[0];   // [B, C, T_IN] fp32
    const float* path = (const float*)d_in[1];   // [B, T_IN, T_OUT] fp32
    float* out = (float*)d_out;                  // [B, C, T_OUT] fp32

    const size_t idx_bytes = (size_t)LR_B * LR_TOUT * sizeof(int);
    if (ws_size >= idx_bytes) {
        int* idx = (int*)d_ws;
        lr_idx9<<<dim3(NTILE, LR_B), 512, 0, stream>>>(path, idx);
        lr_gather5<<<dim3(LR_C / CCHUNK, LR_B), 256, 0, stream>>>(x, idx, out);
    } else {
        lr_fused5<<<dim3(LR_TOUT / 64, LR_B), 256, 0, stream>>>(x, path, out);
    }
}